// Round 3
// baseline (212.648 us; speedup 1.0000x reference)
//
#include <hip/hip_runtime.h>
#include <cstdint>
#include <cstddef>

// DotProductAttention: O = softmax_q(QK^T/8 + log(mask)) @ V
// P = mask * exp(QK^T/8); L[b,k] = sum_q P; O = P @ (diag(1/L) V).
// R3: compute S^T via swapped MFMA operands (A=K, B=Q). C-layout then gives
// each lane 4 consecutive-k' values at fixed q: mask reads become float4,
// P writes become ds_write_b64 into row-major P (PV A-frags stay b128 reads).
// exp2-folding: Qb pre-scaled by 0.125*log2(e) so exp is a bare v_exp_f32.

#define LSEQ 2048
#define DHEAD 64

typedef __bf16 v8bf __attribute__((ext_vector_type(8)));
typedef __bf16 v4bf __attribute__((ext_vector_type(4)));
typedef float v4f __attribute__((ext_vector_type(4)));

#define MFMA16(a, b, c) __builtin_amdgcn_mfma_f32_16x16x32_bf16(a, b, c, 0, 0, 0)

#if __has_builtin(__builtin_amdgcn_exp2f)
#define EXP2F(x) __builtin_amdgcn_exp2f(x)
#else
#define EXP2F(x) __expf((x) * 0.6931471805599453f)
#endif

__device__ __forceinline__ void gl_lds16(const void* g, void* l) {
  __builtin_amdgcn_global_load_lds(
      (__attribute__((address_space(1))) void*)g,
      (__attribute__((address_space(3))) void*)l, 16, 0, 0);
}

// ---- K0: cast Q,K fp32 -> bf16; Q pre-scaled by 0.125*log2(e) ---------------
__global__ __launch_bounds__(256) void cast_qk(const float* __restrict__ Q,
                                               const float* __restrict__ K,
                                               __bf16* __restrict__ Qb,
                                               __bf16* __restrict__ Kb) {
  const float S = 0.18033688011112042f;  // 0.125 * log2(e)
  size_t i = ((size_t)blockIdx.x * 256 + threadIdx.x) * 4;
  float4 q = *(const float4*)(Q + i);
  float4 k = *(const float4*)(K + i);
  v4bf qo = {(__bf16)(q.x * S), (__bf16)(q.y * S), (__bf16)(q.z * S), (__bf16)(q.w * S)};
  v4bf ko = {(__bf16)k.x, (__bf16)k.y, (__bf16)k.z, (__bf16)k.w};
  *(v4bf*)(Qb + i) = qo;
  *(v4bf*)(Kb + i) = ko;
}

// ---- K1: partial column sums Lpart[b,k][qc] = sum_{q in chunk} mask*exp ----
// Grid: b(16) x qchunk(4) x ktile(32) = 2048 WGs -> 8 WGs/CU.
// S^T tiles: lane holds col q=n, rows k' = quad*4+r (consecutive!).
__global__ __launch_bounds__(256) void stats_k(const __bf16* __restrict__ Qb,
                                               const __bf16* __restrict__ Kb,
                                               const float* __restrict__ mask,
                                               float* __restrict__ Lpart) {
  const int bx = blockIdx.x;
  const int b = bx >> 7;
  const int qc = (bx >> 5) & 3;
  const int k0 = (bx & 31) * 64;
  const int tid = threadIdx.x;
  const int wave = tid >> 6, lane = tid & 63;
  const int quad = lane >> 4, n = lane & 15;

  __shared__ __align__(16) __bf16 Qt[64 * 64];
  __shared__ __align__(16) float psum[4][64];

  // Persistent K A-frags: A[m=k'][d]: lane n -> K[k0+sub*16+n][dh*32+quad*8+j]
  v8bf ak[4][2];
#pragma unroll
  for (int sub = 0; sub < 4; ++sub)
#pragma unroll
    for (int dh = 0; dh < 2; ++dh)
      ak[sub][dh] = *(const v8bf*)(Kb + ((size_t)b * LSEQ + k0 + sub * 16 + n) * DHEAD +
                                   dh * 32 + quad * 8);

  float colsum[4][4];
#pragma unroll
  for (int s = 0; s < 4; ++s)
#pragma unroll
    for (int r = 0; r < 4; ++r) colsum[s][r] = 0.f;

  const int qbeg = qc * 512;
  for (int q0 = qbeg; q0 < qbeg + 512; q0 += 64) {
    __syncthreads();
#pragma unroll
    for (int i = 0; i < 2; ++i) {
      int s = (wave * 2 + i) * 64 + lane;
      int row = s >> 3, gc = (s & 7) ^ (row & 7);
      gl_lds16(Qb + ((size_t)b * LSEQ + q0 + row) * DHEAD + gc * 8, &Qt[s * 8]);
    }
    __syncthreads();

    // Q B-frags: B[d][q]: lane n = q-col -> Qt[wave*16+n][quad*8+j]
    v8bf bq[2];
    const int qr = wave * 16 + n;
#pragma unroll
    for (int dh = 0; dh < 2; ++dh)
      bq[dh] = *(const v8bf*)&Qt[qr * 64 + ((dh * 4 + quad) ^ (qr & 7)) * 8];

#pragma unroll
    for (int sub = 0; sub < 4; ++sub) {
      v4f c = {0.f, 0.f, 0.f, 0.f};
      c = MFMA16(ak[sub][0], bq[0], c);
      c = MFMA16(ak[sub][1], bq[1], c);
      // mask[qg][kg..kg+3], qg = q0+wave*16+n (col), kg = k0+sub*16+quad*4
      const float4 m4 = *(const float4*)&mask[(size_t)(q0 + wave * 16 + n) * LSEQ +
                                              k0 + sub * 16 + quad * 4];
#pragma unroll
      for (int r = 0; r < 4; ++r)
        colsum[sub][r] += ((const float*)&m4)[r] * EXP2F(c[r]);
    }
  }

  // butterfly over q-cols (n bits: 1,2,4,8); quad bits (16,32) untouched
#pragma unroll
  for (int sub = 0; sub < 4; ++sub) {
#pragma unroll
    for (int r = 0; r < 4; ++r) {
      float v = colsum[sub][r];
      v += __shfl_xor(v, 1);
      v += __shfl_xor(v, 2);
      v += __shfl_xor(v, 4);
      v += __shfl_xor(v, 8);
      colsum[sub][r] = v;
    }
    if (n == 0) {
      v4f w = {colsum[sub][0], colsum[sub][1], colsum[sub][2], colsum[sub][3]};
      *(v4f*)&psum[wave][sub * 16 + quad * 4] = w;
    }
  }
  __syncthreads();
  if (tid < 64) {
    float s = psum[0][tid] + psum[1][tid] + psum[2][tid] + psum[3][tid];
    Lpart[((size_t)b * LSEQ + k0 + tid) * 4 + qc] = s;
  }
}

// ---- K2: Vts[b][v][k] = bf16(V[b][k][v] / L[b][k]), L = sum of 4 partials --
__global__ __launch_bounds__(256) void vtrans_k(const float* __restrict__ V,
                                                const float* __restrict__ Lpart,
                                                __bf16* __restrict__ Vts) {
  const int b = blockIdx.x >> 6;
  const int k0 = (blockIdx.x & 63) * 32;
  const int tid = threadIdx.x;
  __shared__ float tile[32][65];
  __shared__ float invl[32];
  if (tid < 32) {
    float4 lp = *(const float4*)&Lpart[((size_t)b * LSEQ + k0 + tid) * 4];
    invl[tid] = 1.0f / (lp.x + lp.y + lp.z + lp.w);
  }
#pragma unroll
  for (int t = 0; t < 8; ++t) {
    int flat = t * 256 + tid;
    int k = flat >> 6, v = flat & 63;
    tile[k][v] = V[((size_t)b * LSEQ + k0 + k) * DHEAD + v];
  }
  __syncthreads();
#pragma unroll
  for (int t = 0; t < 8; ++t) {
    int flat = t * 256 + tid;
    int v = flat >> 5, k = flat & 31;
    Vts[((size_t)b * DHEAD + v) * LSEQ + k0 + k] = (__bf16)(tile[k][v] * invl[k]);
  }
}

// ---- K3: O += P_chunk @ Vts; S^T via swapped operands -----------------------
// Grid: b(16) x kchunk(4) x qtile(32) = 2048 WGs; LDS 25.6KB -> 6 WGs/CU.
__global__ __launch_bounds__(256) void attn_k(const __bf16* __restrict__ Qb,
                                              const __bf16* __restrict__ Kb,
                                              const __bf16* __restrict__ Vts,
                                              const float* __restrict__ mask,
                                              float* __restrict__ out) {
  const int bx = blockIdx.x;
  const int b = bx >> 7;
  const int kc = (bx >> 5) & 3;
  const int q0 = (bx & 31) * 64;
  const int tid = threadIdx.x;
  const int wave = tid >> 6, lane = tid & 63;
  const int quad = lane >> 4, n = lane & 15;

  __shared__ __align__(16) __bf16 Kt[64 * 64];
  __shared__ __align__(16) __bf16 Vt[64 * 64];
  __shared__ __align__(16) __bf16 Pt[64 * 72];  // row-major P[q][k'], +8 pad

  // Q B-frags persistent: B[d][q]: lane n = q-col
  v8bf bq[2];
  {
    const int qr = q0 + wave * 16 + n;
#pragma unroll
    for (int dh = 0; dh < 2; ++dh)
      bq[dh] = *(const v8bf*)(Qb + ((size_t)b * LSEQ + qr) * DHEAD + dh * 32 + quad * 8);
  }

  v4f acc[4];
#pragma unroll
  for (int vs = 0; vs < 4; ++vs) acc[vs] = (v4f){0.f, 0.f, 0.f, 0.f};

  const int kbeg = kc * 512;
  for (int k0 = kbeg; k0 < kbeg + 512; k0 += 64) {
    __syncthreads();
#pragma unroll
    for (int i = 0; i < 2; ++i) {
      int s = (wave * 2 + i) * 64 + lane;
      int row = s >> 3, gc = (s & 7) ^ (row & 7);
      gl_lds16(Kb + ((size_t)b * LSEQ + k0 + row) * DHEAD + gc * 8, &Kt[s * 8]);
      gl_lds16(Vts + ((size_t)b * DHEAD + row) * LSEQ + k0 + gc * 8, &Vt[s * 8]);
    }
    __syncthreads();

    // S^T tile: A = K-frag (lane row k' = sub*16+n), B = Q-frag.
    // C layout: lane holds col q=n, rows k' = sub*16+quad*4+{0..3} consecutive.
#pragma unroll
    for (int sub = 0; sub < 4; ++sub) {
      v4f c = {0.f, 0.f, 0.f, 0.f};
      const int kr = sub * 16 + n;
#pragma unroll
      for (int dh = 0; dh < 2; ++dh) {
        v8bf akf = *(const v8bf*)&Kt[kr * 64 + ((dh * 4 + quad) ^ (kr & 7)) * 8];
        c = MFMA16(akf, bq[dh], c);
      }
      const float4 m4 = *(const float4*)&mask[(size_t)(q0 + wave * 16 + n) * LSEQ +
                                              k0 + sub * 16 + quad * 4];
      v4bf pw;
#pragma unroll
      for (int r = 0; r < 4; ++r)
        pw[r] = (__bf16)(((const float*)&m4)[r] * EXP2F(c[r]));
      *(v4bf*)&Pt[(wave * 16 + n) * 72 + sub * 16 + quad * 4] = pw;
    }
    __asm__ volatile("s_waitcnt lgkmcnt(0)" ::: "memory");  // P visible in-wave

    // O += P @ Vt  (A = P rows of own wave, contiguous b128 reads)
#pragma unroll
    for (int kk = 0; kk < 2; ++kk) {
      v8bf ap = *(const v8bf*)&Pt[(wave * 16 + n) * 72 + kk * 32 + quad * 8];
#pragma unroll
      for (int vs = 0; vs < 4; ++vs) {
        const int vr = vs * 16 + n;
        v8bf bv = *(const v8bf*)&Vt[vr * 64 + ((kk * 4 + quad) ^ (vr & 7)) * 8];
        acc[vs] = MFMA16(ap, bv, acc[vs]);
      }
    }
  }

#pragma unroll
  for (int vs = 0; vs < 4; ++vs)
#pragma unroll
    for (int r = 0; r < 4; ++r)
      unsafeAtomicAdd(
          &out[((size_t)b * LSEQ + q0 + wave * 16 + quad * 4 + r) * DHEAD + vs * 16 + n],
          acc[vs][r]);
}

extern "C" void kernel_launch(void* const* d_in, const int* in_sizes, int n_in,
                              void* d_out, int out_size, void* d_ws, size_t ws_size,
                              hipStream_t stream) {
  const float* Q = (const float*)d_in[0];
  const float* K = (const float*)d_in[1];
  const float* V = (const float*)d_in[2];
  const float* mask = (const float*)d_in[3];
  float* out = (float*)d_out;

  char* ws = (char*)d_ws;
  // ws layout: Qb 4 MiB | Kb 4 MiB | Vts 4 MiB. Lpart (512 KiB) is staged in
  // d_out, which is consumed by vtrans_k BEFORE the memset that attn_k needs.
  __bf16* Qb = (__bf16*)(ws);
  __bf16* Kb = (__bf16*)(ws + 4194304);
  __bf16* Vts = (__bf16*)(ws + 8388608);
  float* Lpart = (float*)d_out;
  if (ws_size < 12582912) return;  // workspace too small — fail loudly

  cast_qk<<<2048, 256, 0, stream>>>(Q, K, Qb, Kb);
  stats_k<<<2048, 256, 0, stream>>>(Qb, Kb, mask, Lpart);
  vtrans_k<<<1024, 256, 0, stream>>>(V, Lpart, Vts);
  hipMemsetAsync(out, 0, (size_t)out_size * sizeof(float), stream);
  attn_k<<<2048, 256, 0, stream>>>(Qb, Kb, Vts, mask, out);
}

// Round 4
// 189.280 us; speedup vs baseline: 1.1235x; 1.1235x over previous
//
#include <hip/hip_runtime.h>
#include <cstdint>
#include <cstddef>

// DotProductAttention: O = softmax_q(QK^T/8 + log(mask)) @ V
// P = mask * exp(QK^T/8); L[b,k] = sum_q P; O = P @ (diag(1/L) V).
// R4: R3's S^T layout + software-pipelined mask prefetch. __syncthreads drains
// vmcnt(0) (structural), so mask float4s for iter i+1 are issued between the
// staging issue and the barrier of iter i — they complete during the drain the
// barrier pays anyway; compute never waits on VMEM. Register rotate (mcur/mnxt)
// also pins VGPR allocation up, preventing R3's 40-VGPR load serialization.

#define LSEQ 2048
#define DHEAD 64

typedef __bf16 v8bf __attribute__((ext_vector_type(8)));
typedef __bf16 v4bf __attribute__((ext_vector_type(4)));
typedef float v4f __attribute__((ext_vector_type(4)));

#define MFMA16(a, b, c) __builtin_amdgcn_mfma_f32_16x16x32_bf16(a, b, c, 0, 0, 0)

#if __has_builtin(__builtin_amdgcn_exp2f)
#define EXP2F(x) __builtin_amdgcn_exp2f(x)
#else
#define EXP2F(x) __expf((x) * 0.6931471805599453f)
#endif

__device__ __forceinline__ void gl_lds16(const void* g, void* l) {
  __builtin_amdgcn_global_load_lds(
      (__attribute__((address_space(1))) void*)g,
      (__attribute__((address_space(3))) void*)l, 16, 0, 0);
}

// ---- K0: cast Q,K fp32 -> bf16; Q pre-scaled by 0.125*log2(e) ---------------
__global__ __launch_bounds__(256) void cast_qk(const float* __restrict__ Q,
                                               const float* __restrict__ K,
                                               __bf16* __restrict__ Qb,
                                               __bf16* __restrict__ Kb) {
  const float S = 0.18033688011112042f;  // 0.125 * log2(e)
  size_t i = ((size_t)blockIdx.x * 256 + threadIdx.x) * 4;
  float4 q = *(const float4*)(Q + i);
  float4 k = *(const float4*)(K + i);
  v4bf qo = {(__bf16)(q.x * S), (__bf16)(q.y * S), (__bf16)(q.z * S), (__bf16)(q.w * S)};
  v4bf ko = {(__bf16)k.x, (__bf16)k.y, (__bf16)k.z, (__bf16)k.w};
  *(v4bf*)(Qb + i) = qo;
  *(v4bf*)(Kb + i) = ko;
}

// ---- K1: partial column sums Lpart[b,k][qc] = sum_{q in chunk} mask*exp ----
// Grid: b(16) x qchunk(4) x ktile(32) = 2048 WGs.
__global__ __launch_bounds__(256) void stats_k(const __bf16* __restrict__ Qb,
                                               const __bf16* __restrict__ Kb,
                                               const float* __restrict__ mask,
                                               float* __restrict__ Lpart) {
  const int bx = blockIdx.x;
  const int b = bx >> 7;
  const int qc = (bx >> 5) & 3;
  const int k0 = (bx & 31) * 64;
  const int tid = threadIdx.x;
  const int wave = tid >> 6, lane = tid & 63;
  const int quad = lane >> 4, n = lane & 15;

  __shared__ __align__(16) __bf16 Qt[64 * 64];
  __shared__ __align__(16) float psum[4][64];

  // Persistent K A-frags: A[m=k'][d]: lane n -> K[k0+sub*16+n][dh*32+quad*8+j]
  v8bf ak[4][2];
#pragma unroll
  for (int sub = 0; sub < 4; ++sub)
#pragma unroll
    for (int dh = 0; dh < 2; ++dh)
      ak[sub][dh] = *(const v8bf*)(Kb + ((size_t)b * LSEQ + k0 + sub * 16 + n) * DHEAD +
                                   dh * 32 + quad * 8);

  float colsum[4][4];
#pragma unroll
  for (int s = 0; s < 4; ++s)
#pragma unroll
    for (int r = 0; r < 4; ++r) colsum[s][r] = 0.f;

  const int qbeg = qc * 512;
  // mask column block for this lane is fixed: col = k0 + sub*16 + quad*4
  float4 mcur[4], mnxt[4];
#pragma unroll
  for (int sub = 0; sub < 4; ++sub)
    mnxt[sub] = *(const float4*)&mask[(size_t)(qbeg + wave * 16 + n) * LSEQ + k0 +
                                      sub * 16 + quad * 4];

  for (int q0 = qbeg; q0 < qbeg + 512; q0 += 64) {
    __syncthreads();
#pragma unroll
    for (int i = 0; i < 2; ++i) {
      int s = (wave * 2 + i) * 64 + lane;
      int row = s >> 3, gc = (s & 7) ^ (row & 7);
      gl_lds16(Qb + ((size_t)b * LSEQ + q0 + row) * DHEAD + gc * 8, &Qt[s * 8]);
    }
    // rotate mask regs; prefetch next q-iter (wrap keeps addresses valid)
#pragma unroll
    for (int sub = 0; sub < 4; ++sub) mcur[sub] = mnxt[sub];
    const int qn = (q0 + 64 < qbeg + 512) ? q0 + 64 : qbeg;
#pragma unroll
    for (int sub = 0; sub < 4; ++sub)
      mnxt[sub] = *(const float4*)&mask[(size_t)(qn + wave * 16 + n) * LSEQ + k0 +
                                        sub * 16 + quad * 4];
    __syncthreads();

    // Q B-frags: B[d][q]: lane n = q-col -> Qt[wave*16+n][quad*8+j]
    v8bf bq[2];
    const int qr = wave * 16 + n;
#pragma unroll
    for (int dh = 0; dh < 2; ++dh)
      bq[dh] = *(const v8bf*)&Qt[qr * 64 + ((dh * 4 + quad) ^ (qr & 7)) * 8];

#pragma unroll
    for (int sub = 0; sub < 4; ++sub) {
      v4f c = {0.f, 0.f, 0.f, 0.f};
      c = MFMA16(ak[sub][0], bq[0], c);
      c = MFMA16(ak[sub][1], bq[1], c);
#pragma unroll
      for (int r = 0; r < 4; ++r)
        colsum[sub][r] += ((const float*)&mcur[sub])[r] * EXP2F(c[r]);
    }
  }

  // butterfly over q-cols (n bits: 1,2,4,8); quad bits (16,32) untouched
#pragma unroll
  for (int sub = 0; sub < 4; ++sub) {
#pragma unroll
    for (int r = 0; r < 4; ++r) {
      float v = colsum[sub][r];
      v += __shfl_xor(v, 1);
      v += __shfl_xor(v, 2);
      v += __shfl_xor(v, 4);
      v += __shfl_xor(v, 8);
      colsum[sub][r] = v;
    }
    if (n == 0) {
      v4f w = {colsum[sub][0], colsum[sub][1], colsum[sub][2], colsum[sub][3]};
      *(v4f*)&psum[wave][sub * 16 + quad * 4] = w;
    }
  }
  __syncthreads();
  if (tid < 64) {
    float s = psum[0][tid] + psum[1][tid] + psum[2][tid] + psum[3][tid];
    Lpart[((size_t)b * LSEQ + k0 + tid) * 4 + qc] = s;
  }
}

// ---- K2: Vts[b][v][k] = bf16(V[b][k][v] / L[b][k]), L = sum of 4 partials --
__global__ __launch_bounds__(256) void vtrans_k(const float* __restrict__ V,
                                                const float* __restrict__ Lpart,
                                                __bf16* __restrict__ Vts) {
  const int b = blockIdx.x >> 6;
  const int k0 = (blockIdx.x & 63) * 32;
  const int tid = threadIdx.x;
  __shared__ float tile[32][65];
  __shared__ float invl[32];
  if (tid < 32) {
    float4 lp = *(const float4*)&Lpart[((size_t)b * LSEQ + k0 + tid) * 4];
    invl[tid] = 1.0f / (lp.x + lp.y + lp.z + lp.w);
  }
#pragma unroll
  for (int t = 0; t < 8; ++t) {
    int flat = t * 256 + tid;
    int k = flat >> 6, v = flat & 63;
    tile[k][v] = V[((size_t)b * LSEQ + k0 + k) * DHEAD + v];
  }
  __syncthreads();
#pragma unroll
  for (int t = 0; t < 8; ++t) {
    int flat = t * 256 + tid;
    int v = flat >> 5, k = flat & 31;
    Vts[((size_t)b * DHEAD + v) * LSEQ + k0 + k] = (__bf16)(tile[k][v] * invl[k]);
  }
}

// ---- K3: O += P_chunk @ Vts; S^T via swapped operands -----------------------
// Grid: b(16) x kchunk(4) x qtile(32) = 2048 WGs; LDS 25.6KB -> 6 WGs/CU.
__global__ __launch_bounds__(256) void attn_k(const __bf16* __restrict__ Qb,
                                              const __bf16* __restrict__ Kb,
                                              const __bf16* __restrict__ Vts,
                                              const float* __restrict__ mask,
                                              float* __restrict__ out) {
  const int bx = blockIdx.x;
  const int b = bx >> 7;
  const int kc = (bx >> 5) & 3;
  const int q0 = (bx & 31) * 64;
  const int tid = threadIdx.x;
  const int wave = tid >> 6, lane = tid & 63;
  const int quad = lane >> 4, n = lane & 15;

  __shared__ __align__(16) __bf16 Kt[64 * 64];
  __shared__ __align__(16) __bf16 Vt[64 * 64];
  __shared__ __align__(16) __bf16 Pt[64 * 72];  // row-major P[q][k'], +8 pad

  // Q B-frags persistent: B[d][q]: lane n = q-col
  v8bf bq[2];
  {
    const int qr = q0 + wave * 16 + n;
#pragma unroll
    for (int dh = 0; dh < 2; ++dh)
      bq[dh] = *(const v8bf*)(Qb + ((size_t)b * LSEQ + qr) * DHEAD + dh * 32 + quad * 8);
  }

  v4f acc[4];
#pragma unroll
  for (int vs = 0; vs < 4; ++vs) acc[vs] = (v4f){0.f, 0.f, 0.f, 0.f};

  const int kbeg = kc * 512;
  // this lane's mask row is fixed (col q = n); k-block advances per iter
  const float* mrow = &mask[(size_t)(q0 + wave * 16 + n) * LSEQ];
  float4 mcur[4], mnxt[4];
#pragma unroll
  for (int sub = 0; sub < 4; ++sub)
    mnxt[sub] = *(const float4*)&mrow[kbeg + sub * 16 + quad * 4];

  for (int k0 = kbeg; k0 < kbeg + 512; k0 += 64) {
    __syncthreads();
#pragma unroll
    for (int i = 0; i < 2; ++i) {
      int s = (wave * 2 + i) * 64 + lane;
      int row = s >> 3, gc = (s & 7) ^ (row & 7);
      gl_lds16(Kb + ((size_t)b * LSEQ + k0 + row) * DHEAD + gc * 8, &Kt[s * 8]);
      gl_lds16(Vts + ((size_t)b * DHEAD + row) * LSEQ + k0 + gc * 8, &Vt[s * 8]);
    }
    // rotate mask regs; prefetch next k-iter (completes during barrier drain)
#pragma unroll
    for (int sub = 0; sub < 4; ++sub) mcur[sub] = mnxt[sub];
    const int kn = (k0 + 64 < kbeg + 512) ? k0 + 64 : kbeg;
#pragma unroll
    for (int sub = 0; sub < 4; ++sub)
      mnxt[sub] = *(const float4*)&mrow[kn + sub * 16 + quad * 4];
    __syncthreads();

    // S^T tile: A = K-frag (lane row k' = sub*16+n), B = Q-frag.
    // C layout: lane holds col q=n, rows k' = sub*16+quad*4+{0..3} consecutive.
#pragma unroll
    for (int sub = 0; sub < 4; ++sub) {
      v4f c = {0.f, 0.f, 0.f, 0.f};
      const int kr = sub * 16 + n;
#pragma unroll
      for (int dh = 0; dh < 2; ++dh) {
        v8bf akf = *(const v8bf*)&Kt[kr * 64 + ((dh * 4 + quad) ^ (kr & 7)) * 8];
        c = MFMA16(akf, bq[dh], c);
      }
      v4bf pw;
#pragma unroll
      for (int r = 0; r < 4; ++r)
        pw[r] = (__bf16)(((const float*)&mcur[sub])[r] * EXP2F(c[r]));
      *(v4bf*)&Pt[(wave * 16 + n) * 72 + sub * 16 + quad * 4] = pw;
    }
    __asm__ volatile("s_waitcnt lgkmcnt(0)" ::: "memory");  // P visible in-wave

    // O += P @ Vt  (A = P rows of own wave, contiguous b128 reads)
#pragma unroll
    for (int kk = 0; kk < 2; ++kk) {
      v8bf ap = *(const v8bf*)&Pt[(wave * 16 + n) * 72 + kk * 32 + quad * 8];
#pragma unroll
      for (int vs = 0; vs < 4; ++vs) {
        const int vr = vs * 16 + n;
        v8bf bv = *(const v8bf*)&Vt[vr * 64 + ((kk * 4 + quad) ^ (vr & 7)) * 8];
        acc[vs] = MFMA16(ap, bv, acc[vs]);
      }
    }
  }

#pragma unroll
  for (int vs = 0; vs < 4; ++vs)
#pragma unroll
    for (int r = 0; r < 4; ++r)
      unsafeAtomicAdd(
          &out[((size_t)b * LSEQ + q0 + wave * 16 + quad * 4 + r) * DHEAD + vs * 16 + n],
          acc[vs][r]);
}

extern "C" void kernel_launch(void* const* d_in, const int* in_sizes, int n_in,
                              void* d_out, int out_size, void* d_ws, size_t ws_size,
                              hipStream_t stream) {
  const float* Q = (const float*)d_in[0];
  const float* K = (const float*)d_in[1];
  const float* V = (const float*)d_in[2];
  const float* mask = (const float*)d_in[3];
  float* out = (float*)d_out;

  char* ws = (char*)d_ws;
  // ws layout: Qb 4 MiB | Kb 4 MiB | Vts 4 MiB. Lpart (512 KiB) staged in
  // d_out, consumed by vtrans_k BEFORE the memset that attn_k needs.
  __bf16* Qb = (__bf16*)(ws);
  __bf16* Kb = (__bf16*)(ws + 4194304);
  __bf16* Vts = (__bf16*)(ws + 8388608);
  float* Lpart = (float*)d_out;
  if (ws_size < 12582912) return;  // workspace too small — fail loudly

  cast_qk<<<2048, 256, 0, stream>>>(Q, K, Qb, Kb);
  stats_k<<<2048, 256, 0, stream>>>(Qb, Kb, mask, Lpart);
  vtrans_k<<<1024, 256, 0, stream>>>(V, Lpart, Vts);
  hipMemsetAsync(out, 0, (size_t)out_size * sizeof(float), stream);
  attn_k<<<2048, 256, 0, stream>>>(Qb, Kb, Vts, mask, out);
}